// Round 2
// baseline (451.057 us; speedup 1.0000x reference)
//
#include <hip/hip_runtime.h>
#include <math.h>

#define TILE 32
#define DM   64
#define DI   128
#define NLAY 4
#define XS   68     // sx/sob row stride (floats): 17 16B-chunks -> bank-group +1/row
#define XZS  260    // sxz row stride (floats): 65 chunks

__device__ __forceinline__ int swz(int r, int c) {
  // XOR-swizzle 16B chunks by (row>>3) so rows 8 apart hit different banks
  return (c ^ (((r >> 3) & 7) << 2));
}
__device__ __forceinline__ float siluf(float v) {
  return v / (1.f + __expf(-v));
}
__device__ __forceinline__ float softplusf(float v) {
  return v > 20.f ? v : log1pf(__expf(v));
}

// ---------------------------------------------------------------------------
// Prologue: fold (x[:, :12] @ w_nr + b_nr) @ w_in_nr + b_in_nr into a single
// 12x64 weight + 64 bias (same for rain branch, 4x64). Writes to ws:
//   [0..768)    Wf_nr (12x64)
//   [768..832)  bf_nr (64)
//   [832..1088) Wf_r  (4x64)
//   [1088..1152) bf_r (64)
// ---------------------------------------------------------------------------
extern "C" __global__ __launch_bounds__(256)
void fuse_weights_kernel(const float* __restrict__ w_nr, const float* __restrict__ b_nr,
                         const float* __restrict__ w_r,  const float* __restrict__ b_r,
                         const float* __restrict__ win_nr, const float* __restrict__ bin_nr,
                         const float* __restrict__ win_r,  const float* __restrict__ bin_r,
                         float* __restrict__ ws) {
  __shared__ float snr[1000];
  __shared__ float sr_[1000];
  const int j = blockIdx.x;      // output column 0..63
  const int tid = threadIdx.x;
  for (int k = tid; k < 1000; k += 256) {
    snr[k] = win_nr[(size_t)k * 64 + j];
    sr_[k] = win_r [(size_t)k * 64 + j];
  }
  __syncthreads();
  const int grp = tid >> 4;   // 16 groups of 16 lanes
  const int ks  = tid & 15;
  for (int o = grp; o < 18; o += 16) {
    float acc = 0.f;
    if (o < 12) {
      const float* s = w_nr + (size_t)o * 1000;
      for (int k = ks; k < 1000; k += 16) acc = fmaf(s[k], snr[k], acc);
    } else if (o == 12) {
      for (int k = ks; k < 1000; k += 16) acc = fmaf(b_nr[k], snr[k], acc);
    } else if (o < 17) {
      const float* s = w_r + (size_t)(o - 13) * 1000;
      for (int k = ks; k < 1000; k += 16) acc = fmaf(s[k], sr_[k], acc);
    } else {
      for (int k = ks; k < 1000; k += 16) acc = fmaf(b_r[k], sr_[k], acc);
    }
    for (int off = 1; off < 16; off <<= 1) acc += __shfl_xor(acc, off, 64);
    if (ks == 0) {
      if (o < 12)       ws[o * 64 + j] = acc;
      else if (o == 12) ws[768 + j]  = acc + bin_nr[j];
      else if (o < 17)  ws[832 + (o - 13) * 64 + j] = acc;
      else              ws[1088 + j] = acc + bin_r[j];
    }
  }
}

// ---------------------------------------------------------------------------
// Main fused kernel: 512 blocks x 256 threads. Each block owns TILE=32 rows,
// runs both branches through all 4 layers + head, everything in LDS.
// ---------------------------------------------------------------------------
extern "C" __global__ __launch_bounds__(256, 2)
void mamba_main_kernel(const float* __restrict__ xin, const float* __restrict__ ws,
                       const float* __restrict__ ipw, const float* __restrict__ cw,
                       const float* __restrict__ cbi, const float* __restrict__ xpw,
                       const float* __restrict__ dtw, const float* __restrict__ dtb,
                       const float* __restrict__ dskip, const float* __restrict__ opw,
                       const float* __restrict__ lng, const float* __restrict__ lnb,
                       const float* __restrict__ hw1, const float* __restrict__ hb1,
                       const float* __restrict__ hw2, const float* __restrict__ hb2,
                       float* __restrict__ outp)
{
  __shared__ __align__(16) float sx[2][TILE * XS];   // residual streams (nr, r)
  __shared__ __align__(16) float sxz[TILE * XZS];    // xz -> (xc|z) -> (y|z)
  __shared__ __align__(16) float sproj[TILE * 48];   // proj (36, padded)
  __shared__ __align__(16) float sob[TILE * XS];     // mamba output
  __shared__ float sbc[TILE];
  __shared__ float smean[TILE];
  __shared__ float srstd[TILE];

  const int tid = threadIdx.x;
  const int r0  = blockIdx.x * TILE;
  const int wv   = tid >> 6;     // wave 0..3
  const int lane = tid & 63;

  // ---- Phase 0: x0 = feat @ Wf + bf (folded through NC)
  for (int idx = tid; idx < 2 * TILE * DM; idx += 256) {
    int br = idx >> 11;          // TILE*DM = 2048
    int rc = idx & 2047;
    int r = rc >> 6, c = rc & 63;
    const float* xr = xin + (size_t)(r0 + r) * 16;
    float acc;
    if (br == 0) {
      acc = ws[768 + c];
      #pragma unroll
      for (int i = 0; i < 12; ++i) acc = fmaf(xr[i], ws[i * 64 + c], acc);
    } else {
      acc = ws[1088 + c];
      #pragma unroll
      for (int i = 0; i < 4; ++i) acc = fmaf(xr[12 + i], ws[832 + i * 64 + c], acc);
    }
    sx[br][r * XS + swz(r, c)] = acc;
  }

  for (int l = 0; l < NLAY; ++l) {
    for (int b = 0; b < 2; ++b) {
      __syncthreads();
      // ---- Phase 1: xz = x @ ipw[l] (32x256, K=64); conv tap3 + silu on xc half
      {
        const int cbk = lane & 7;        // 8 col-blocks of 8
        const int rg  = lane >> 3;       // 8 row-groups of 4
        const int c0  = wv * 64 + cbk * 8;
        const int rb  = rg * 4;
        const float* W = ipw + (size_t)l * DM * 2 * DI;
        float acc[4][8];
        #pragma unroll
        for (int i = 0; i < 4; ++i)
          #pragma unroll
          for (int j = 0; j < 8; ++j) acc[i][j] = 0.f;
        for (int k = 0; k < DM; k += 4) {
          float4 xk[4];
          #pragma unroll
          for (int rr = 0; rr < 4; ++rr)
            xk[rr] = *(const float4*)&sx[b][(rb + rr) * XS + swz(rb + rr, k)];
          #pragma unroll
          for (int kk = 0; kk < 4; ++kk) {
            float4 w0 = *(const float4*)&W[(size_t)(k + kk) * 256 + c0];
            float4 w1 = *(const float4*)&W[(size_t)(k + kk) * 256 + c0 + 4];
            #pragma unroll
            for (int rr = 0; rr < 4; ++rr) {
              float xv = (&xk[rr].x)[kk];
              acc[rr][0] = fmaf(xv, w0.x, acc[rr][0]);
              acc[rr][1] = fmaf(xv, w0.y, acc[rr][1]);
              acc[rr][2] = fmaf(xv, w0.z, acc[rr][2]);
              acc[rr][3] = fmaf(xv, w0.w, acc[rr][3]);
              acc[rr][4] = fmaf(xv, w1.x, acc[rr][4]);
              acc[rr][5] = fmaf(xv, w1.y, acc[rr][5]);
              acc[rr][6] = fmaf(xv, w1.z, acc[rr][6]);
              acc[rr][7] = fmaf(xv, w1.w, acc[rr][7]);
            }
          }
        }
        if (c0 < DI) {   // wave-uniform: waves 0,1 = xc half, waves 2,3 = z half
          float c3[8], cc[8];
          #pragma unroll
          for (int j = 0; j < 8; ++j) {
            c3[j] = cw[(size_t)l * DI * 4 + (c0 + j) * 4 + 3];
            cc[j] = cbi[(size_t)l * DI + c0 + j];
          }
          #pragma unroll
          for (int rr = 0; rr < 4; ++rr)
            #pragma unroll
            for (int j = 0; j < 8; ++j) {
              float v = fmaf(acc[rr][j], c3[j], cc[j]);
              acc[rr][j] = siluf(v);
            }
        }
        #pragma unroll
        for (int rr = 0; rr < 4; ++rr) {
          int r = rb + rr;
          *(float4*)&sxz[r * XZS + swz(r, c0)]     = make_float4(acc[rr][0], acc[rr][1], acc[rr][2], acc[rr][3]);
          *(float4*)&sxz[r * XZS + swz(r, c0 + 4)] = make_float4(acc[rr][4], acc[rr][5], acc[rr][6], acc[rr][7]);
        }
      }
      __syncthreads();
      // ---- Phase 2: proj = xc @ xpw[l] (32x36, K=128); 36 = 9 blocks of 4 cols
      {
        const int cblk = tid & 15;
        const int rg   = tid >> 4;       // 16 groups of 2 rows
        if (cblk < 9) {
          const int c0 = cblk * 4;
          const float* W = xpw + (size_t)l * DI * 36;
          float acc[2][4];
          #pragma unroll
          for (int i = 0; i < 2; ++i)
            #pragma unroll
            for (int j = 0; j < 4; ++j) acc[i][j] = 0.f;
          for (int k = 0; k < DI; k += 4) {
            float4 xk[2];
            #pragma unroll
            for (int rr = 0; rr < 2; ++rr) {
              int r = rg * 2 + rr;
              xk[rr] = *(const float4*)&sxz[r * XZS + swz(r, k)];
            }
            #pragma unroll
            for (int kk = 0; kk < 4; ++kk) {
              float4 w0 = *(const float4*)&W[(size_t)(k + kk) * 36 + c0];
              #pragma unroll
              for (int rr = 0; rr < 2; ++rr) {
                float xv = (&xk[rr].x)[kk];
                acc[rr][0] = fmaf(xv, w0.x, acc[rr][0]);
                acc[rr][1] = fmaf(xv, w0.y, acc[rr][1]);
                acc[rr][2] = fmaf(xv, w0.z, acc[rr][2]);
                acc[rr][3] = fmaf(xv, w0.w, acc[rr][3]);
              }
            }
          }
          #pragma unroll
          for (int rr = 0; rr < 2; ++rr) {
            int r = rg * 2 + rr;
            *(float4*)&sproj[r * 48 + c0] = make_float4(acc[rr][0], acc[rr][1], acc[rr][2], acc[rr][3]);
          }
        }
      }
      __syncthreads();
      // ---- Phase 3: bc[r] = Bm . Cm (per-row scalar; scan collapses at L=1)
      if (tid < TILE) {
        int r = tid;
        float bcv = 0.f;
        #pragma unroll
        for (int s = 0; s < 16; ++s)
          bcv = fmaf(sproj[r * 48 + 4 + s], sproj[r * 48 + 20 + s], bcv);
        sbc[r] = bcv;
      }
      __syncthreads();
      // ---- Phase 4: dt = softplus(proj[:, :4]@dtw + dtb); y = xc*(dt*bc+dskip)*silu(z)
      {
        const int d  = tid & 127;
        const int hf = tid >> 7;
        const float w0 = dtw[(size_t)l * 4 * DI + 0 * DI + d];
        const float w1 = dtw[(size_t)l * 4 * DI + 1 * DI + d];
        const float w2 = dtw[(size_t)l * 4 * DI + 2 * DI + d];
        const float w3 = dtw[(size_t)l * 4 * DI + 3 * DI + d];
        const float bb = dtb[(size_t)l * DI + d];
        const float ds = dskip[(size_t)l * DI + d];
        #pragma unroll
        for (int rr = 0; rr < 16; ++rr) {
          int r = hf * 16 + rr;
          float4 pj = *(const float4*)&sproj[r * 48];
          float dtv = bb;
          dtv = fmaf(pj.x, w0, dtv);
          dtv = fmaf(pj.y, w1, dtv);
          dtv = fmaf(pj.z, w2, dtv);
          dtv = fmaf(pj.w, w3, dtv);
          dtv = softplusf(dtv);
          float xcv = sxz[r * XZS + swz(r, d)];
          float zv  = sxz[r * XZS + swz(r, d + 128)];
          float yv = xcv * fmaf(dtv, sbc[r], ds) * siluf(zv);
          sxz[r * XZS + swz(r, d)] = yv;   // overwrite xc with y
        }
      }
      __syncthreads();
      // ---- Phase 5: o = y @ opw[l] (32x64, K=128)
      {
        const int cbk = lane & 1;
        const int r   = lane >> 1;       // one row per thread
        const int c0  = wv * 16 + cbk * 8;
        const float* W = opw + (size_t)l * DI * DM;
        float acc[8];
        #pragma unroll
        for (int j = 0; j < 8; ++j) acc[j] = 0.f;
        for (int k = 0; k < DI; k += 4) {
          float4 xk = *(const float4*)&sxz[r * XZS + swz(r, k)];
          #pragma unroll
          for (int kk = 0; kk < 4; ++kk) {
            float4 w0 = *(const float4*)&W[(size_t)(k + kk) * 64 + c0];
            float4 w1 = *(const float4*)&W[(size_t)(k + kk) * 64 + c0 + 4];
            float xv = (&xk.x)[kk];
            acc[0] = fmaf(xv, w0.x, acc[0]); acc[1] = fmaf(xv, w0.y, acc[1]);
            acc[2] = fmaf(xv, w0.z, acc[2]); acc[3] = fmaf(xv, w0.w, acc[3]);
            acc[4] = fmaf(xv, w1.x, acc[4]); acc[5] = fmaf(xv, w1.y, acc[5]);
            acc[6] = fmaf(xv, w1.z, acc[6]); acc[7] = fmaf(xv, w1.w, acc[7]);
          }
        }
        *(float4*)&sob[r * XS + swz(r, c0)]     = make_float4(acc[0], acc[1], acc[2], acc[3]);
        *(float4*)&sob[r * XS + swz(r, c0 + 4)] = make_float4(acc[4], acc[5], acc[6], acc[7]);
      }
      __syncthreads();
      // ---- Phase 6a: LayerNorm stats
      if (tid < TILE) {
        int r = tid;
        float s = 0.f, s2 = 0.f;
        for (int c = 0; c < DM; c += 4) {
          float4 v = *(const float4*)&sob[r * XS + swz(r, c)];
          s  += v.x + v.y + v.z + v.w;
          s2 += v.x * v.x + v.y * v.y + v.z * v.z + v.w * v.w;
        }
        float m = s * (1.f / DM);
        float var = s2 * (1.f / DM) - m * m;
        smean[r] = m;
        srstd[r] = rsqrtf(var + 1e-5f);
      }
      __syncthreads();
      // ---- Phase 6b: x += LN(o)*g + b
      for (int idx = tid; idx < TILE * DM; idx += 256) {
        int r = idx >> 6, c = idx & 63;
        float o = sob[r * XS + swz(r, c)];
        float v = fmaf((o - smean[r]) * srstd[r], lng[(size_t)l * DM + c], lnb[(size_t)l * DM + c]);
        sx[b][r * XS + swz(r, c)] += v;
      }
    }
  }
  __syncthreads();
  // ---- Head: h1 = relu([x_nr, x_r] @ hw1 + hb1); out = h1 @ hw2 + hb2
  for (int idx = tid; idx < TILE * 32; idx += 256) {
    int r = idx >> 5, c = idx & 31;
    float acc = hb1[c];
    for (int k = 0; k < DM; ++k)
      acc = fmaf(sx[0][r * XS + swz(r, k)], hw1[(size_t)k * 32 + c], acc);
    for (int k = 0; k < DM; ++k)
      acc = fmaf(sx[1][r * XS + swz(r, k)], hw1[(size_t)(DM + k) * 32 + c], acc);
    sproj[r * 48 + c] = fmaxf(acc, 0.f);
  }
  __syncthreads();
  if (tid < TILE) {
    int r = tid;
    float acc = hb2[0];
    #pragma unroll
    for (int k = 0; k < 32; ++k)
      acc = fmaf(sproj[r * 48 + k], hw2[k], acc);
    outp[r0 + r] = acc;
  }
}

extern "C" void kernel_launch(void* const* d_in, const int* in_sizes, int n_in,
                              void* d_out, int out_size, void* d_ws, size_t ws_size,
                              hipStream_t stream) {
  const float* x      = (const float*)d_in[0];
  const float* w_nr   = (const float*)d_in[1];
  const float* b_nr   = (const float*)d_in[2];
  const float* w_r    = (const float*)d_in[3];
  const float* b_r    = (const float*)d_in[4];
  const float* win_nr = (const float*)d_in[5];
  const float* bin_nr = (const float*)d_in[6];
  const float* win_r  = (const float*)d_in[7];
  const float* bin_r  = (const float*)d_in[8];
  const float* ipw    = (const float*)d_in[9];
  const float* cw     = (const float*)d_in[10];
  const float* cb     = (const float*)d_in[11];
  const float* xpw    = (const float*)d_in[12];
  const float* dtw    = (const float*)d_in[13];
  const float* dtb    = (const float*)d_in[14];
  // d_in[15] = alog: dead code at L=1 (scan from h=0 uses only dBx)
  const float* dskip  = (const float*)d_in[16];
  const float* opw    = (const float*)d_in[17];
  const float* lng    = (const float*)d_in[18];
  const float* lnb    = (const float*)d_in[19];
  const float* hw1    = (const float*)d_in[20];
  const float* hb1    = (const float*)d_in[21];
  const float* hw2    = (const float*)d_in[22];
  const float* hb2    = (const float*)d_in[23];
  float* ws  = (float*)d_ws;
  float* out = (float*)d_out;

  fuse_weights_kernel<<<64, 256, 0, stream>>>(w_nr, b_nr, w_r, b_r,
                                              win_nr, bin_nr, win_r, bin_r, ws);
  mamba_main_kernel<<<16384 / TILE, 256, 0, stream>>>(x, ws, ipw, cw, cb, xpw,
                                                      dtw, dtb, dskip, opw,
                                                      lng, lnb, hw1, hb1, hw2, hb2, out);
}

// Round 4
// 348.245 us; speedup vs baseline: 1.2952x; 1.2952x over previous
//
#include <hip/hip_runtime.h>
#include <math.h>

typedef unsigned short u16;
typedef unsigned int u32;
typedef __attribute__((ext_vector_type(8))) short bf8v;   // 8 bf16 in 4 VGPRs
typedef __attribute__((ext_vector_type(4))) float f32x4;

#define BR   16      // batch rows per block
#define LR   32      // logical rows (2 branches merged: same layer weights!)
#define DM   64
#define DI   128
#define NLAY 4

// ws layout (ushort indices). Floats [0..1152) hold folded input proj (fp32).
#define U_IPH 4096                       // ipwT hi  [4][256][64]
#define U_IPL (U_IPH + 4*16384)          // ipwT lo
#define U_XPH (U_IPL + 4*16384)          // xpwT hi  [4][48][128] (cols>=36 zero)
#define U_XPL (U_XPH + 4*6144)
#define U_OPH (U_XPL + 4*6144)           // opwT hi  [4][64][128]
#define U_OPL (U_OPH + 4*8192)           // end = 249856 u16 = 488 KiB

__device__ __forceinline__ float b2f(u16 u) {
  u32 x = ((u32)u) << 16; return __uint_as_float(x);
}
__device__ __forceinline__ u16 f2b(float f) {     // round-to-nearest-even
  u32 u = __float_as_uint(f);
  u32 r = (u + 0x7FFFu + ((u >> 16) & 1u)) >> 16;
  return (u16)r;
}
__device__ __forceinline__ void splitbf(float v, u16& h, u16& l) {
  h = f2b(v); l = f2b(v - b2f(h));
}
__device__ __forceinline__ float siluf(float v) { return v / (1.f + __expf(-v)); }
__device__ __forceinline__ float softplusf(float v) {
  return v > 20.f ? v : log1pf(__expf(v));
}
// XOR-swizzled LDS indices (u16 units; 16B chunk = 8 elems) — conflict-free b128
__device__ __forceinline__ int sxIdx(int r, int c) {     // residual [32][64]
  return r * 64 + ((((c >> 3) ^ r) & 7) << 3) + ((c >> 3) & ~7) * 8 + (c & 7);
}
__device__ __forceinline__ int xzIdx(int r, int c) {     // xz [32][256]
  int ch = (c >> 3); int chs = (ch & ~7) | ((ch ^ r) & 7);
  return r * 256 + chs * 8 + (c & 7);
}

#define MFMA16(A, B, C) __builtin_amdgcn_mfma_f32_16x16x32_bf16(A, B, C, 0, 0, 0)

// ---------------------------------------------------------------------------
// Prologue A: fold (x@w+b)@w_in+b_in through NC=1000 -> 12x64 / 4x64 fp32
// ---------------------------------------------------------------------------
extern "C" __global__ __launch_bounds__(256)
void fuse_weights_kernel(const float* __restrict__ w_nr, const float* __restrict__ b_nr,
                         const float* __restrict__ w_r,  const float* __restrict__ b_r,
                         const float* __restrict__ win_nr, const float* __restrict__ bin_nr,
                         const float* __restrict__ win_r,  const float* __restrict__ bin_r,
                         float* __restrict__ ws) {
  __shared__ float snr[1000];
  __shared__ float sr_[1000];
  const int j = blockIdx.x;
  const int tid = threadIdx.x;
  for (int k = tid; k < 1000; k += 256) {
    snr[k] = win_nr[(size_t)k * 64 + j];
    sr_[k] = win_r [(size_t)k * 64 + j];
  }
  __syncthreads();
  const int grp = tid >> 4;
  const int ks  = tid & 15;
  for (int o = grp; o < 18; o += 16) {
    float acc = 0.f;
    if (o < 12) {
      const float* s = w_nr + (size_t)o * 1000;
      for (int k = ks; k < 1000; k += 16) acc = fmaf(s[k], snr[k], acc);
    } else if (o == 12) {
      for (int k = ks; k < 1000; k += 16) acc = fmaf(b_nr[k], snr[k], acc);
    } else if (o < 17) {
      const float* s = w_r + (size_t)(o - 13) * 1000;
      for (int k = ks; k < 1000; k += 16) acc = fmaf(s[k], sr_[k], acc);
    } else {
      for (int k = ks; k < 1000; k += 16) acc = fmaf(b_r[k], sr_[k], acc);
    }
    for (int off = 1; off < 16; off <<= 1) acc += __shfl_xor(acc, off, 64);
    if (ks == 0) {
      if (o < 12)       ws[o * 64 + j] = acc;
      else if (o == 12) ws[768 + j]  = acc + bin_nr[j];
      else if (o < 17)  ws[832 + (o - 13) * 64 + j] = acc;
      else              ws[1088 + j] = acc + bin_r[j];
    }
  }
}

// ---------------------------------------------------------------------------
// Prologue B: transpose + bf16 hi/lo split of ipw/xpw/opw into ws
// ---------------------------------------------------------------------------
extern "C" __global__ __launch_bounds__(256)
void prep_weights_kernel(const float* __restrict__ ipw, const float* __restrict__ xpw,
                         const float* __restrict__ opw, u16* __restrict__ wsu) {
  const int PER_L = 16384 + 6144 + 8192;   // 30720
  int gid = blockIdx.x * 256 + threadIdx.x;
  if (gid >= 4 * PER_L) return;
  int l = gid / PER_L, rem = gid - l * PER_L;
  float v; int dh, dl;
  if (rem < 16384) {               // ipw [64k][256n] -> ipwT [256][64]
    int n = rem >> 6, k = rem & 63;
    v = ipw[(size_t)l * 16384 + k * 256 + n];
    int o = l * 16384 + n * 64 + k;
    dh = U_IPH + o; dl = U_IPL + o;
  } else if (rem < 22528) {        // xpw [128k][36n] -> xpwT [48][128]
    int r2 = rem - 16384, n = r2 >> 7, k = r2 & 127;
    v = (n < 36) ? xpw[(size_t)l * 4608 + k * 36 + n] : 0.f;
    int o = l * 6144 + n * 128 + k;
    dh = U_XPH + o; dl = U_XPL + o;
  } else {                         // opw [128k][64n] -> opwT [64][128]
    int r3 = rem - 22528, n = r3 >> 7, k = r3 & 127;
    v = opw[(size_t)l * 8192 + k * 64 + n];
    int o = l * 8192 + n * 128 + k;
    dh = U_OPH + o; dl = U_OPL + o;
  }
  u16 h, lo; splitbf(v, h, lo);
  wsu[dh] = h; wsu[dl] = lo;
}

// ---------------------------------------------------------------------------
// Main: 1024 blocks x 512 threads. Block = 16 batch rows x 2 branches = 32
// logical rows (branches share all layer weights). GEMMs via bf16x3 MFMA
// (Ah*Bh + Al*Bh + Ah*Bl, fp32 accum): ~2^-16 rel error. Glue fp32.
// ---------------------------------------------------------------------------
extern "C" __global__ __launch_bounds__(512, 4)
void mamba_main_kernel(const float* __restrict__ xin, const float* __restrict__ wsf,
                       const u16* __restrict__ wsu,
                       const float* __restrict__ cw, const float* __restrict__ cbi,
                       const float* __restrict__ dtw, const float* __restrict__ dtb,
                       const float* __restrict__ dskip,
                       const float* __restrict__ lng, const float* __restrict__ lnb,
                       const float* __restrict__ hw1, const float* __restrict__ hb1,
                       const float* __restrict__ hw2, const float* __restrict__ hb2,
                       float* __restrict__ outp)
{
  __shared__ __align__(16) u16 sxh[LR * 64], sxl[LR * 64];     // residual hi/lo
  __shared__ __align__(16) u16 szh[LR * 256], szl[LR * 256];   // xz / (y|silu z)
  __shared__ __align__(16) float sproj[LR * 48];
  __shared__ float spart[4][LR][2];
  __shared__ float sbc[LR], smean[LR], srstd[LR];

  const int tid = threadIdx.x;
  const int wv = tid >> 6, lane = tid & 63;
  const int col16 = lane & 15, g = lane >> 4;
  const int r0 = blockIdx.x * BR;

  // ---- Phase 0: x0 = feat @ Wf + bf; rows 0-15 branch nr, 16-31 branch r
  for (int idx = tid; idx < LR * 64; idx += 512) {
    int r = idx >> 6, c = idx & 63;
    const float* xr = xin + (size_t)(r0 + (r & 15)) * 16;
    float acc;
    if (r < 16) {
      acc = wsf[768 + c];
      #pragma unroll
      for (int i = 0; i < 12; ++i) acc = fmaf(xr[i], wsf[i * 64 + c], acc);
    } else {
      acc = wsf[1088 + c];
      #pragma unroll
      for (int i = 0; i < 4; ++i) acc = fmaf(xr[12 + i], wsf[832 + i * 64 + c], acc);
    }
    u16 h, lo; splitbf(acc, h, lo);
    int di = sxIdx(r, c); sxh[di] = h; sxl[di] = lo;
  }

  for (int l = 0; l < NLAY; ++l) {
    __syncthreads();
    // ---- Phase 1: xz = x @ ipwT  (32x256, K=64) + conv tap3 + silu
    {
      const int rt = wv & 1;
      const int ct0 = (wv >> 1) * 4;          // 4 col-tiles per wave
      const int rowA = rt * 16 + col16;       // A row for this lane
      f32x4 Cf[4] = {{0,0,0,0},{0,0,0,0},{0,0,0,0},{0,0,0,0}};
      #pragma unroll
      for (int ks = 0; ks < 2; ++ks) {
        int ai = rowA * 64 + ((((ks * 4 + g) ^ rowA) & 7) << 3);
        bf8v Ah = *(const bf8v*)&sxh[ai];
        bf8v Al = *(const bf8v*)&sxl[ai];
        #pragma unroll
        for (int t = 0; t < 4; ++t) {
          int n = (ct0 + t) * 16 + col16;
          size_t bo = (size_t)l * 16384 + n * 64 + ks * 32 + g * 8;
          bf8v Wh = *(const bf8v*)&wsu[U_IPH + bo];
          bf8v Wl = *(const bf8v*)&wsu[U_IPL + bo];
          Cf[t] = MFMA16(Ah, Wh, Cf[t]);
          Cf[t] = MFMA16(Al, Wh, Cf[t]);
          Cf[t] = MFMA16(Ah, Wl, Cf[t]);
        }
      }
      const bool isXC = (ct0 < 8);            // wave-uniform
      #pragma unroll
      for (int t = 0; t < 4; ++t) {
        int col = (ct0 + t) * 16 + col16;
        float c3 = 0.f, cc = 0.f;
        if (isXC) {
          c3 = cw[(size_t)l * 512 + col * 4 + 3];
          cc = cbi[(size_t)l * 128 + col];
        }
        #pragma unroll
        for (int j = 0; j < 4; ++j) {
          int row = rt * 16 + g * 4 + j;
          float v = Cf[t][j];
          if (isXC) v = fmaf(v, c3, cc);      // conv collapses to tap3 at L=1
          v = siluf(v);                       // silu(xc) or silu(z)
          u16 h, lo; splitbf(v, h, lo);
          int di = xzIdx(row, col);
          szh[di] = h; szl[di] = lo;
        }
      }
    }
    __syncthreads();
    // ---- Phase 2: proj = xc @ xpwT (32x48, K=128); waves 0-5
    if (wv < 6) {
      const int rt = wv & 1, ct = wv >> 1;
      const int rowA = rt * 16 + col16;
      f32x4 C = {0, 0, 0, 0};
      #pragma unroll
      for (int ks = 0; ks < 4; ++ks) {
        int ch = ks * 4 + g;                  // K-chunk 0..15
        int ai = rowA * 256 + (((ch & ~7) | ((ch ^ rowA) & 7)) << 3);
        bf8v Ah = *(const bf8v*)&szh[ai];
        bf8v Al = *(const bf8v*)&szl[ai];
        int n = ct * 16 + col16;
        size_t bo = (size_t)l * 6144 + n * 128 + ks * 32 + g * 8;
        bf8v Wh = *(const bf8v*)&wsu[U_XPH + bo];
        bf8v Wl = *(const bf8v*)&wsu[U_XPL + bo];
        C = MFMA16(Ah, Wh, C);
        C = MFMA16(Al, Wh, C);
        C = MFMA16(Ah, Wl, C);
      }
      #pragma unroll
      for (int j = 0; j < 4; ++j) {
        int row = rt * 16 + g * 4 + j, col = ct * 16 + col16;
        sproj[row * 48 + col] = C[j];
      }
    }
    __syncthreads();
    // ---- Phase 3: bc[r] = Bm . Cm (scan collapses: h = dBx at L=1)
    {
      int r = tid >> 4, s = tid & 15;
      float v = sproj[r * 48 + 4 + s] * sproj[r * 48 + 20 + s];
      v += __shfl_xor(v, 1); v += __shfl_xor(v, 2);
      v += __shfl_xor(v, 4); v += __shfl_xor(v, 8);
      if (s == 0) sbc[r] = v;
    }
    __syncthreads();
    // ---- Phase 4: dt = softplus(proj[:, :4]@dtw+dtb); y = xc*(dt*bc+ds)*silu(z)
    {
      int d = tid & 127, rg = tid >> 7;
      float w0 = dtw[(size_t)l * 512 + d];
      float w1 = dtw[(size_t)l * 512 + 128 + d];
      float w2 = dtw[(size_t)l * 512 + 256 + d];
      float w3 = dtw[(size_t)l * 512 + 384 + d];
      float bb = dtb[(size_t)l * 128 + d];
      float ds = dskip[(size_t)l * 128 + d];
      #pragma unroll
      for (int rr = 0; rr < 8; ++rr) {
        int r = rg * 8 + rr;
        float p0 = sproj[r * 48 + 0], p1 = sproj[r * 48 + 1];
        float p2 = sproj[r * 48 + 2], p3 = sproj[r * 48 + 3];
        float dtv = softplusf(fmaf(p3, w3, fmaf(p2, w2, fmaf(p1, w1, fmaf(p0, w0, bb)))));
        int ix = xzIdx(r, d), iz = xzIdx(r, d + 128);
        float xc = b2f(szh[ix]) + b2f(szl[ix]);
        float sz = b2f(szh[iz]) + b2f(szl[iz]);   // already silu(z)
        float y = xc * fmaf(dtv, sbc[r], ds) * sz;
        u16 h, lo; splitbf(y, h, lo);
        szh[ix] = h; szl[ix] = lo;                // overwrite xc with y
      }
    }
    __syncthreads();
    // ---- Phase 5: o = y @ opwT (32x64, K=128); 1 tile per wave; keep frag
    f32x4 O = {0, 0, 0, 0};
    {
      const int rt = wv & 1, ct = wv >> 1;
      const int rowA = rt * 16 + col16;
      #pragma unroll
      for (int ks = 0; ks < 4; ++ks) {
        int ch = ks * 4 + g;                  // K-chunk 0..15
        int ai = rowA * 256 + (((ch & ~7) | ((ch ^ rowA) & 7)) << 3);
        bf8v Ah = *(const bf8v*)&szh[ai];
        bf8v Al = *(const bf8v*)&szl[ai];
        int n = ct * 16 + col16;
        size_t bo = (size_t)l * 8192 + n * 128 + ks * 32 + g * 8;
        bf8v Wh = *(const bf8v*)&wsu[U_OPH + bo];
        bf8v Wl = *(const bf8v*)&wsu[U_OPL + bo];
        O = MFMA16(Ah, Wh, O);
        O = MFMA16(Al, Wh, O);
        O = MFMA16(Ah, Wl, O);
      }
      #pragma unroll
      for (int j = 0; j < 4; ++j) {              // per-row LN partials
        float s1 = O[j], s2 = O[j] * O[j];
        s1 += __shfl_xor(s1, 1); s2 += __shfl_xor(s2, 1);
        s1 += __shfl_xor(s1, 2); s2 += __shfl_xor(s2, 2);
        s1 += __shfl_xor(s1, 4); s2 += __shfl_xor(s2, 4);
        s1 += __shfl_xor(s1, 8); s2 += __shfl_xor(s2, 8);
        if (col16 == 0) {
          int row = rt * 16 + g * 4 + j;
          spart[ct][row][0] = s1; spart[ct][row][1] = s2;
        }
      }
    }
    __syncthreads();
    // ---- Phase 6a: LN stats
    if (tid < LR) {
      int r = tid;
      float s1 = spart[0][r][0] + spart[1][r][0] + spart[2][r][0] + spart[3][r][0];
      float s2 = spart[0][r][1] + spart[1][r][1] + spart[2][r][1] + spart[3][r][1];
      float m = s1 * (1.f / 64);
      float var = s2 * (1.f / 64) - m * m;
      smean[r] = m; srstd[r] = rsqrtf(var + 1e-5f);
    }
    __syncthreads();
    // ---- Phase 6b: x += LN(o)*g + b  (O frags still live in regs)
    {
      const int rt = wv & 1, ct = wv >> 1;
      int col = ct * 16 + col16;
      float gv = lng[(size_t)l * 64 + col], bv = lnb[(size_t)l * 64 + col];
      #pragma unroll
      for (int j = 0; j < 4; ++j) {
        int row = rt * 16 + g * 4 + j;
        float v = fmaf((O[j] - smean[row]) * srstd[row], gv, bv);
        int di = sxIdx(row, col);
        float nv = b2f(sxh[di]) + b2f(sxl[di]) + v;
        u16 h, lo; splitbf(nv, h, lo);
        sxh[di] = h; sxl[di] = lo;
      }
    }
  }
  __syncthreads();
  // ---- Head: h1 = relu([x_nr|x_r] @ hw1 + hb1); out = h1 @ hw2 + hb2
  {
    int rr = tid >> 5, c = tid & 31;
    float acc = hb1[c];
    for (int k = 0; k < 64; ++k) {
      int d0 = sxIdx(rr, k);
      acc = fmaf(b2f(sxh[d0]) + b2f(sxl[d0]), hw1[(size_t)k * 32 + c], acc);
    }
    for (int k = 0; k < 64; ++k) {
      int d1 = sxIdx(rr + 16, k);
      acc = fmaf(b2f(sxh[d1]) + b2f(sxl[d1]), hw1[(size_t)(64 + k) * 32 + c], acc);
    }
    sproj[rr * 48 + c] = fmaxf(acc, 0.f);
  }
  __syncthreads();
  if (tid < BR) {
    float acc = hb2[0];
    #pragma unroll
    for (int k = 0; k < 32; ++k) acc = fmaf(sproj[tid * 48 + k], hw2[k], acc);
    outp[r0 + tid] = acc;
  }
}

extern "C" void kernel_launch(void* const* d_in, const int* in_sizes, int n_in,
                              void* d_out, int out_size, void* d_ws, size_t ws_size,
                              hipStream_t stream) {
  const float* x      = (const float*)d_in[0];
  const float* w_nr   = (const float*)d_in[1];
  const float* b_nr   = (const float*)d_in[2];
  const float* w_r    = (const float*)d_in[3];
  const float* b_r    = (const float*)d_in[4];
  const float* win_nr = (const float*)d_in[5];
  const float* bin_nr = (const float*)d_in[6];
  const float* win_r  = (const float*)d_in[7];
  const float* bin_r  = (const float*)d_in[8];
  const float* ipw    = (const float*)d_in[9];
  const float* cw     = (const float*)d_in[10];
  const float* cb     = (const float*)d_in[11];
  const float* xpw    = (const float*)d_in[12];
  const float* dtw    = (const float*)d_in[13];
  const float* dtb    = (const float*)d_in[14];
  // d_in[15] = alog: dead at L=1 (scan from h=0 uses only dBx)
  const float* dskip  = (const float*)d_in[16];
  const float* opw    = (const float*)d_in[17];
  const float* lng    = (const float*)d_in[18];
  const float* lnb    = (const float*)d_in[19];
  const float* hw1    = (const float*)d_in[20];
  const float* hb1    = (const float*)d_in[21];
  const float* hw2    = (const float*)d_in[22];
  const float* hb2    = (const float*)d_in[23];
  float* wsf = (float*)d_ws;
  u16*   wsu = (u16*)d_ws;
  float* out = (float*)d_out;

  fuse_weights_kernel<<<64, 256, 0, stream>>>(w_nr, b_nr, w_r, b_r,
                                              win_nr, bin_nr, win_r, bin_r, wsf);
  prep_weights_kernel<<<480, 256, 0, stream>>>(ipw, xpw, opw, wsu);
  mamba_main_kernel<<<16384 / BR, 512, 0, stream>>>(x, wsf, wsu, cw, cb,
                                                    dtw, dtb, dskip, lng, lnb,
                                                    hw1, hb1, hw2, hb2, out);
}